// Round 9
// baseline (176.213 us; speedup 1.0000x reference)
//
#include <hip/hip_runtime.h>
#include <stdint.h>

#define D_FEAT 64
#define NEG_INF_BITS 0xFF800000u
#define ENC_NEG_INF  0x007FFFFFu   // order-preserving encoding of -inf
#define NPB 32                      // nodes per bucket (= 1 << BSHIFT)
#define BSHIFT 5
#define BM_BLOCK 256                // bucket_max threads (4 waves) — proven config
#define MAXB 4096                   // max buckets (N <= 131072 at NPB=32)
#define PL_BLOCKS 512               // place: 2 blocks/CU, 16 waves/CU
#define PL_THREADS 512
#define O_CAP 65536                 // overflow side-list entries (never hit on sane data)

// Order-preserving float->uint: enc monotone increasing with float value.
__device__ __forceinline__ unsigned enc_f32(float v) {
    unsigned b = __float_as_uint(v);
    return ((int)b >= 0) ? (b ^ 0x80000000u) : ~b;
}
__device__ __forceinline__ unsigned dec_bits(unsigned u) {
    // decoded float bits; ENC_NEG_INF maps to 0.0f
    if (u == ENC_NEG_INF) return 0u;
    return (u & 0x80000000u) ? (u ^ 0x80000000u) : ~u;
}

// ---------- D2: place into fixed-stride buckets (LDS count -> one reservation atomic
// per (block,bucket) -> LDS cursors). No hist/scan dispatches needed.
// Intra-bucket order nondeterministic; max is order-independent -> bit-exact.
__global__ void __launch_bounds__(PL_THREADS)
place_kernel(const int* __restrict__ src, const int* __restrict__ dst,
             int* __restrict__ cnt, int* __restrict__ ovf_cnt,
             int* __restrict__ ovf_dst, int* __restrict__ ovf_src,
             unsigned* __restrict__ packed,
             int E, int Te, int B, int cap, int aligned4) {
    __shared__ int lh[MAXB];
    int t = blockIdx.x;
    int beg = t * Te;
    int end = min(E, beg + Te);
    if (beg >= end) return;                      // block-uniform, before any sync
    for (int i = threadIdx.x; i < B; i += blockDim.x) lh[i] = 0;
    __syncthreads();
    int nE = end - beg;
    int n4 = aligned4 ? (nE >> 2) : 0;           // beg is a multiple of 4
    const int4* d4 = (const int4*)(dst + beg);
    // pass 1: count this chunk
    for (int k = threadIdx.x; k < n4; k += blockDim.x) {
        int4 d = d4[k];
        atomicAdd(&lh[d.x >> BSHIFT], 1);
        atomicAdd(&lh[d.y >> BSHIFT], 1);
        atomicAdd(&lh[d.z >> BSHIFT], 1);
        atomicAdd(&lh[d.w >> BSHIFT], 1);
    }
    for (int i = beg + (n4 << 2) + threadIdx.x; i < end; i += blockDim.x)
        atomicAdd(&lh[dst[i] >> BSHIFT], 1);
    __syncthreads();
    // reserve contiguous per-bucket slot ranges (global slot index within bucket)
    for (int i = threadIdx.x; i < B; i += blockDim.x) {
        int c = lh[i];
        lh[i] = c ? atomicAdd(&cnt[i], c) : 0;
    }
    __syncthreads();
    // pass 2: place (chunk is L2-hot from pass 1)
    for (int i = beg + threadIdx.x; i < end; i += blockDim.x) {
        int d = dst[i];
        int s = src[i];
        int b = d >> BSHIFT;
        int pos = atomicAdd(&lh[b], 1);          // bucket-global slot
        if (pos < cap) {
            packed[(size_t)b * cap + pos] = (unsigned)s | ((unsigned)(d & (NPB - 1)) << 17);
        } else {
            int o = atomicAdd(ovf_cnt, 1);
            if (o < O_CAP) { ovf_dst[o] = d; ovf_src[o] = s; }
        }
    }
}

// ---------- D3: per-bucket scatter-max in LDS (proven body: lane=feature, 0 conflicts) ----------
__global__ void __launch_bounds__(BM_BLOCK)
bucket_max_kernel(const float* __restrict__ h,
                  const int* __restrict__ cnt, const int* __restrict__ ovf_cnt,
                  const int* __restrict__ ovf_dst, const int* __restrict__ ovf_src,
                  const int* __restrict__ src, const int* __restrict__ dst,
                  const unsigned* __restrict__ packed,
                  float* __restrict__ out, int N, int E, int cap) {
    __shared__ unsigned buf[NPB * D_FEAT];   // 8 KB
    int b = blockIdx.x;
    int tid = threadIdx.x;
    int node0 = b << BSHIFT;
    int nvals = (min(NPB, N - node0)) * D_FEAT;

    for (int i = tid; i < NPB * D_FEAT; i += BM_BLOCK) buf[i] = ENC_NEG_INF;
    __syncthreads();

    int total = cnt[b];
    int beg = b * cap;
    int end = beg + min(total, cap);
    int wid = tid >> 6;
    int lane = tid & 63;

    for (int base = beg + (wid << 6); base < end; base += BM_BLOCK) {
        int nk = min(64, end - base);
        unsigned p = (lane < nk) ? packed[base + lane] : 0u;
        int j = 0;
        for (; j + 8 <= nk; j += 8) {
            unsigned q[8];
            float v[8];
            #pragma unroll
            for (int k = 0; k < 8; ++k) q[k] = (unsigned)__shfl((int)p, j + k);
            #pragma unroll
            for (int k = 0; k < 8; ++k) v[k] = h[(size_t)(q[k] & 0x1FFFFu) * D_FEAT + lane];
            #pragma unroll
            for (int k = 0; k < 8; ++k)
                atomicMax(&buf[(q[k] >> 17) * D_FEAT + lane], enc_f32(v[k]));
        }
        for (; j < nk; ++j) {
            unsigned pj = (unsigned)__shfl((int)p, j);
            float v = h[(size_t)(pj & 0x1FFFFu) * D_FEAT + lane];
            atomicMax(&buf[(pj >> 17) * D_FEAT + lane], enc_f32(v));
        }
    }

    // ---- overflow safety net (ov == 0 on sane data: one broadcast load + branch) ----
    int ov = *ovf_cnt;
    if (ov > 0) {
        if (ov <= O_CAP) {
            for (int i = 0; i < ov; ++i) {           // list entries broadcast to all lanes
                int d = ovf_dst[i];
                if ((d >> BSHIFT) == b) {
                    float v = h[(size_t)ovf_src[i] * D_FEAT + lane];
                    atomicMax(&buf[(d & (NPB - 1)) * D_FEAT + lane], enc_f32(v));
                }
            }
        } else if (total > cap) {
            // truncated list: rescan all edges for this bucket (max is idempotent)
            for (int e = tid; e < E; e += BM_BLOCK) {
                int d = dst[e];
                if ((d >> BSHIFT) == b) {
                    const float* hr = h + (size_t)src[e] * D_FEAT;
                    int row = (d & (NPB - 1)) * D_FEAT;
                    for (int f = 0; f < D_FEAT; ++f)
                        atomicMax(&buf[row + f], enc_f32(hr[f]));
                }
            }
        }
    }
    __syncthreads();

    if (nvals == NPB * D_FEAT) {
        uint4* o4 = (uint4*)(out + (size_t)node0 * D_FEAT);
        const uint4* b4 = (const uint4*)buf;
        for (int i = tid; i < (NPB * D_FEAT) / 4; i += BM_BLOCK) {
            uint4 u = b4[i];
            uint4 r;
            r.x = dec_bits(u.x); r.y = dec_bits(u.y);
            r.z = dec_bits(u.z); r.w = dec_bits(u.w);
            o4[i] = r;
        }
    } else {
        unsigned* o = (unsigned*)(out + (size_t)node0 * D_FEAT);
        for (int i = tid; i < nvals; i += BM_BLOCK) o[i] = dec_bits(buf[i]);
    }
}

// ---------- fallback: atomic scatter (large-N / tiny-ws path) ----------
__global__ void init_out_kernel(uint4* __restrict__ out, int n4) {
    int i = blockIdx.x * blockDim.x + threadIdx.x;
    if (i < n4) {
        uint4 v;
        v.x = NEG_INF_BITS; v.y = NEG_INF_BITS; v.z = NEG_INF_BITS; v.w = NEG_INF_BITS;
        out[i] = v;
    }
}
__global__ void scatter_max_kernel(const float* __restrict__ h, const int* __restrict__ src,
                                   const int* __restrict__ dst, float* __restrict__ out, int E) {
    int gid = blockIdx.x * blockDim.x + threadIdx.x;
    int e = gid >> 6;
    if (e >= E) return;
    int lane = gid & 63;
    float v = h[src[e] * D_FEAT + lane];
    int* addr = (int*)(out + dst[e] * D_FEAT + lane);
    if (v >= 0.0f) atomicMax(addr, __float_as_int(v));
    else           atomicMin((unsigned int*)addr, __float_as_uint(v));
}
__global__ void finalize_kernel(float* __restrict__ out, int n) {
    int i = blockIdx.x * blockDim.x + threadIdx.x;
    if (i < n && __float_as_uint(out[i]) == NEG_INF_BITS) out[i] = 0.0f;
}

// ---------- launch ----------
extern "C" void kernel_launch(void* const* d_in, const int* in_sizes, int n_in,
                              void* d_out, int out_size, void* d_ws, size_t ws_size,
                              hipStream_t stream) {
    const float* h = (const float*)d_in[0];
    const int* edge_index = (const int*)d_in[1];
    int E = in_sizes[1] / 2;                 // edge_index is [2, E] row-major
    const int* src = edge_index;
    const int* dst = edge_index + E;
    float* out = (float*)d_out;
    int N = out_size / D_FEAT;

    int B = (N + NPB - 1) >> BSHIFT;

    // fixed per-bucket capacity: 1.25x mean degree, 64-aligned, floor 128
    int cap = 0;
    if (B > 0) {
        cap = (((E / B) * 5) / 4 + 63) & ~63;
        if (cap < 128) cap = 128;
    }
    size_t need = ((size_t)B + 1 + 2 * (size_t)O_CAP + (size_t)B * cap) * sizeof(int);

    if (N <= (1 << 17) && B <= MAXB && E > 0 && cap > 0 && ws_size >= need) {
        int* cnt         = (int*)d_ws;                   // [B]
        int* ovf_cnt     = cnt + B;                      // [1]
        int* ovf_dst     = ovf_cnt + 1;                  // [O_CAP]
        int* ovf_src     = ovf_dst + O_CAP;              // [O_CAP]
        unsigned* packed = (unsigned*)(ovf_src + O_CAP); // [B*cap]

        int aligned4 = (((((uintptr_t)dst) | ((uintptr_t)src)) & 15) == 0) ? 1 : 0;

        hipMemsetAsync(cnt, 0, (size_t)(B + 1) * sizeof(int), stream);

        int Te = ((E + PL_BLOCKS - 1) / PL_BLOCKS + 3) & ~3;   // chunk, multiple of 4
        place_kernel<<<PL_BLOCKS, PL_THREADS, 0, stream>>>(
            src, dst, cnt, ovf_cnt, ovf_dst, ovf_src, packed, E, Te, B, cap, aligned4);

        bucket_max_kernel<<<B, BM_BLOCK, 0, stream>>>(
            h, cnt, ovf_cnt, ovf_dst, ovf_src, src, dst, packed, out, N, E, cap);
    } else {
        int n4 = out_size / 4;
        init_out_kernel<<<(n4 + 255) / 256, 256, 0, stream>>>((uint4*)out, n4);
        long long total = (long long)E * 64;
        scatter_max_kernel<<<(int)((total + 255) / 256), 256, 0, stream>>>(h, src, dst, out, E);
        finalize_kernel<<<(out_size + 255) / 256, 256, 0, stream>>>(out, out_size);
    }
}

// Round 10
// 155.885 us; speedup vs baseline: 1.1304x; 1.1304x over previous
//
#include <hip/hip_runtime.h>
#include <stdint.h>

#define D_FEAT 64
#define NEG_INF_BITS 0xFF800000u
#define ENC_NEG_INF  0x007FFFFFu   // order-preserving encoding of -inf
#define NPB 64                      // nodes per bucket (= 1 << BSHIFT)
#define BSHIFT 6
#define BM_BLOCK 256                // bucket_max threads (4 waves) — proven config
#define MAXB 2048                   // max buckets (N <= 131072)
#define PL_BLOCKS 256               // place: 1 block/CU
#define PL_THREADS 1024             // 16 waves/CU
#define O_CAP 65536                 // overflow side-list entries (never hit on sane data)

// Order-preserving float->uint: enc monotone increasing with float value.
__device__ __forceinline__ unsigned enc_f32(float v) {
    unsigned b = __float_as_uint(v);
    return ((int)b >= 0) ? (b ^ 0x80000000u) : ~b;
}
__device__ __forceinline__ unsigned dec_bits(unsigned u) {
    // decoded float bits; ENC_NEG_INF maps to 0.0f
    if (u == ENC_NEG_INF) return 0u;
    return (u & 0x80000000u) ? (u ^ 0x80000000u) : ~u;
}

// ---------- D2: place into fixed-stride buckets (LDS count -> one reservation atomic
// per (block,bucket) -> LDS cursors). No hist/scan dispatches needed.
// Intra-bucket order nondeterministic; max is order-independent -> bit-exact.
__global__ void __launch_bounds__(PL_THREADS)
place_kernel(const int* __restrict__ src, const int* __restrict__ dst,
             int* __restrict__ cnt, int* __restrict__ ovf_cnt,
             int* __restrict__ ovf_dst, int* __restrict__ ovf_src,
             unsigned* __restrict__ packed,
             int E, int Te, int B, int cap, int aligned4) {
    __shared__ int lh[MAXB];
    int t = blockIdx.x;
    int beg = t * Te;
    int end = min(E, beg + Te);
    if (beg >= end) return;                      // block-uniform, before any sync
    for (int i = threadIdx.x; i < B; i += blockDim.x) lh[i] = 0;
    __syncthreads();
    int nE = end - beg;
    int n4 = aligned4 ? (nE >> 2) : 0;           // beg is a multiple of 4
    const int4* d4 = (const int4*)(dst + beg);
    // pass 1: count this chunk
    for (int k = threadIdx.x; k < n4; k += blockDim.x) {
        int4 d = d4[k];
        atomicAdd(&lh[d.x >> BSHIFT], 1);
        atomicAdd(&lh[d.y >> BSHIFT], 1);
        atomicAdd(&lh[d.z >> BSHIFT], 1);
        atomicAdd(&lh[d.w >> BSHIFT], 1);
    }
    for (int i = beg + (n4 << 2) + threadIdx.x; i < end; i += blockDim.x)
        atomicAdd(&lh[dst[i] >> BSHIFT], 1);
    __syncthreads();
    // reserve contiguous per-bucket slot ranges (global slot index within bucket)
    for (int i = threadIdx.x; i < B; i += blockDim.x) {
        int c = lh[i];
        lh[i] = c ? atomicAdd(&cnt[i], c) : 0;
    }
    __syncthreads();
    // pass 2: place (chunk is L2-hot from pass 1)
    for (int i = beg + threadIdx.x; i < end; i += blockDim.x) {
        int d = dst[i];
        int s = src[i];
        int b = d >> BSHIFT;
        int pos = atomicAdd(&lh[b], 1);          // bucket-global slot
        if (pos < cap) {
            packed[(size_t)b * cap + pos] = (unsigned)s | ((unsigned)(d & (NPB - 1)) << 17);
        } else {
            int o = atomicAdd(ovf_cnt, 1);
            if (o < O_CAP) { ovf_dst[o] = d; ovf_src[o] = s; }
        }
    }
}

// ---------- D3: per-bucket scatter-max in LDS (proven body: lane=feature, 0 conflicts) ----------
__global__ void __launch_bounds__(BM_BLOCK)
bucket_max_kernel(const float* __restrict__ h,
                  const int* __restrict__ cnt, const int* __restrict__ ovf_cnt,
                  const int* __restrict__ ovf_dst, const int* __restrict__ ovf_src,
                  const int* __restrict__ src, const int* __restrict__ dst,
                  const unsigned* __restrict__ packed,
                  float* __restrict__ out, int N, int E, int cap) {
    __shared__ unsigned buf[NPB * D_FEAT];   // 16 KB
    int b = blockIdx.x;
    int tid = threadIdx.x;
    int node0 = b << BSHIFT;
    int nvals = (min(NPB, N - node0)) * D_FEAT;

    for (int i = tid; i < NPB * D_FEAT; i += BM_BLOCK) buf[i] = ENC_NEG_INF;
    __syncthreads();

    int total = cnt[b];
    int beg = b * cap;
    int end = beg + min(total, cap);
    int wid = tid >> 6;
    int lane = tid & 63;

    for (int base = beg + (wid << 6); base < end; base += BM_BLOCK) {
        int nk = min(64, end - base);
        unsigned p = (lane < nk) ? packed[base + lane] : 0u;
        int j = 0;
        for (; j + 8 <= nk; j += 8) {
            unsigned q[8];
            float v[8];
            #pragma unroll
            for (int k = 0; k < 8; ++k) q[k] = (unsigned)__shfl((int)p, j + k);
            #pragma unroll
            for (int k = 0; k < 8; ++k) v[k] = h[(size_t)(q[k] & 0x1FFFFu) * D_FEAT + lane];
            #pragma unroll
            for (int k = 0; k < 8; ++k)
                atomicMax(&buf[(q[k] >> 17) * D_FEAT + lane], enc_f32(v[k]));
        }
        for (; j < nk; ++j) {
            unsigned pj = (unsigned)__shfl((int)p, j);
            float v = h[(size_t)(pj & 0x1FFFFu) * D_FEAT + lane];
            atomicMax(&buf[(pj >> 17) * D_FEAT + lane], enc_f32(v));
        }
    }

    // ---- overflow safety net (ov == 0 on sane data: one broadcast load + branch) ----
    int ov = *ovf_cnt;
    if (ov > 0) {
        if (ov <= O_CAP) {
            for (int i = 0; i < ov; ++i) {           // list entries broadcast to all lanes
                int d = ovf_dst[i];
                if ((d >> BSHIFT) == b) {
                    float v = h[(size_t)ovf_src[i] * D_FEAT + lane];
                    atomicMax(&buf[(d & (NPB - 1)) * D_FEAT + lane], enc_f32(v));
                }
            }
        } else if (total > cap) {
            // truncated list: rescan all edges for this bucket (max is idempotent)
            for (int e = tid; e < E; e += BM_BLOCK) {
                int d = dst[e];
                if ((d >> BSHIFT) == b) {
                    const float* hr = h + (size_t)src[e] * D_FEAT;
                    int row = (d & (NPB - 1)) * D_FEAT;
                    for (int f = 0; f < D_FEAT; ++f)
                        atomicMax(&buf[row + f], enc_f32(hr[f]));
                }
            }
        }
    }
    __syncthreads();

    if (nvals == NPB * D_FEAT) {
        uint4* o4 = (uint4*)(out + (size_t)node0 * D_FEAT);
        const uint4* b4 = (const uint4*)buf;
        for (int i = tid; i < (NPB * D_FEAT) / 4; i += BM_BLOCK) {
            uint4 u = b4[i];
            uint4 r;
            r.x = dec_bits(u.x); r.y = dec_bits(u.y);
            r.z = dec_bits(u.z); r.w = dec_bits(u.w);
            o4[i] = r;
        }
    } else {
        unsigned* o = (unsigned*)(out + (size_t)node0 * D_FEAT);
        for (int i = tid; i < nvals; i += BM_BLOCK) o[i] = dec_bits(buf[i]);
    }
}

// ---------- fallback: atomic scatter (large-N / tiny-ws path) ----------
__global__ void init_out_kernel(uint4* __restrict__ out, int n4) {
    int i = blockIdx.x * blockDim.x + threadIdx.x;
    if (i < n4) {
        uint4 v;
        v.x = NEG_INF_BITS; v.y = NEG_INF_BITS; v.z = NEG_INF_BITS; v.w = NEG_INF_BITS;
        out[i] = v;
    }
}
__global__ void scatter_max_kernel(const float* __restrict__ h, const int* __restrict__ src,
                                   const int* __restrict__ dst, float* __restrict__ out, int E) {
    int gid = blockIdx.x * blockDim.x + threadIdx.x;
    int e = gid >> 6;
    if (e >= E) return;
    int lane = gid & 63;
    float v = h[src[e] * D_FEAT + lane];
    int* addr = (int*)(out + dst[e] * D_FEAT + lane);
    if (v >= 0.0f) atomicMax(addr, __float_as_int(v));
    else           atomicMin((unsigned int*)addr, __float_as_uint(v));
}
__global__ void finalize_kernel(float* __restrict__ out, int n) {
    int i = blockIdx.x * blockDim.x + threadIdx.x;
    if (i < n && __float_as_uint(out[i]) == NEG_INF_BITS) out[i] = 0.0f;
}

// ---------- launch ----------
extern "C" void kernel_launch(void* const* d_in, const int* in_sizes, int n_in,
                              void* d_out, int out_size, void* d_ws, size_t ws_size,
                              hipStream_t stream) {
    const float* h = (const float*)d_in[0];
    const int* edge_index = (const int*)d_in[1];
    int E = in_sizes[1] / 2;                 // edge_index is [2, E] row-major
    const int* src = edge_index;
    const int* dst = edge_index + E;
    float* out = (float*)d_out;
    int N = out_size / D_FEAT;

    int B = (N + NPB - 1) >> BSHIFT;

    // fixed per-bucket capacity: 1.25x mean degree, 64-aligned, floor 128
    int cap = 0;
    if (B > 0) {
        cap = (((E / B) * 5) / 4 + 63) & ~63;
        if (cap < 128) cap = 128;
    }
    size_t need = ((size_t)B + 1 + 2 * (size_t)O_CAP + (size_t)B * cap) * sizeof(int);

    if (N <= (1 << 17) && B <= MAXB && E > 0 && cap > 0 && ws_size >= need) {
        int* cnt         = (int*)d_ws;                   // [B]
        int* ovf_cnt     = cnt + B;                      // [1]
        int* ovf_dst     = ovf_cnt + 1;                  // [O_CAP]
        int* ovf_src     = ovf_dst + O_CAP;              // [O_CAP]
        unsigned* packed = (unsigned*)(ovf_src + O_CAP); // [B*cap]

        int aligned4 = (((((uintptr_t)dst) | ((uintptr_t)src)) & 15) == 0) ? 1 : 0;

        hipMemsetAsync(cnt, 0, (size_t)(B + 1) * sizeof(int), stream);

        int Te = ((E + PL_BLOCKS - 1) / PL_BLOCKS + 3) & ~3;   // chunk, multiple of 4
        place_kernel<<<PL_BLOCKS, PL_THREADS, 0, stream>>>(
            src, dst, cnt, ovf_cnt, ovf_dst, ovf_src, packed, E, Te, B, cap, aligned4);

        bucket_max_kernel<<<B, BM_BLOCK, 0, stream>>>(
            h, cnt, ovf_cnt, ovf_dst, ovf_src, src, dst, packed, out, N, E, cap);
    } else {
        int n4 = out_size / 4;
        init_out_kernel<<<(n4 + 255) / 256, 256, 0, stream>>>((uint4*)out, n4);
        long long total = (long long)E * 64;
        scatter_max_kernel<<<(int)((total + 255) / 256), 256, 0, stream>>>(h, src, dst, out, E);
        finalize_kernel<<<(out_size + 255) / 256, 256, 0, stream>>>(out, out_size);
    }
}